// Round 9
// baseline (2366.786 us; speedup 1.0000x reference)
//
#include <hip/hip_runtime.h>
#include <stdint.h>

// ---- types ----
typedef __attribute__((ext_vector_type(8))) short short8;   // 8 bf16 = 4 VGPR (MFMA A/B frag)
typedef __attribute__((ext_vector_type(4))) short short4v;  // 4 bf16 = 8B
typedef __attribute__((ext_vector_type(4))) float f32x4;    // MFMA C/D frag
typedef __attribute__((ext_vector_type(4))) unsigned int u32x4;
typedef __attribute__((ext_vector_type(4))) int i32x4;
typedef __attribute__((ext_vector_type(2))) unsigned long long u64x2;

// ---- bf16 helpers (manual RNE) ----
__device__ inline unsigned short f2bf(float f) {
  unsigned int u = __builtin_bit_cast(unsigned int, f);
  u += 0x7fffu + ((u >> 16) & 1u);
  return (unsigned short)(u >> 16);
}
__device__ inline float bf2f(unsigned short s) {
  return __builtin_bit_cast(float, (unsigned int)s << 16);
}

// sentinel = bf16 0x7F7F (=3.39e38). |h|<1 strictly -> cannot collide with data.
// stale64(v) != 0 iff any 16-bit lane of v equals 0x7F7F.
// Protocol invariant: producers store packed 8B words; an 8B word arrives
// atomically, so "no sentinel in the pulled chunk" == chunk ready.
__device__ inline unsigned long long stale64(unsigned long long v) {
  unsigned long long x = v ^ 0x7f7f7f7f7f7f7f7full;
  return (x - 0x0001000100010001ull) & ~x & 0x8000800080008000ull;
}

// Problem constants: B=32, T=512, D=H=1024, 4H=4096, M = T*B = 16384
// gx layout: [t][b][n] bf16, n = permuted gate-row (4*j + gate)
// hs layout: [t][b][j]  bf16

// ---- W: [4096][1024] f32 -> Wp: gate-interleaved rows, bf16. ----
__global__ __launch_bounds__(256) void cvt_w_kernel(const float* __restrict__ W,
                                                    short* __restrict__ Wp) {
  const int total = (4096 * 1024) / 4;
  for (int i = blockIdx.x * blockDim.x + threadIdx.x; i < total;
       i += gridDim.x * blockDim.x) {
    int k4 = i & 255;
    int n  = i >> 8;
    int g = n & 3, j = n >> 2;
    float4 v = *(const float4*)(W + ((size_t)g * 1024 + j) * 1024 + (size_t)k4 * 4);
    short4v o;
    o.x = (short)f2bf(v.x); o.y = (short)f2bf(v.y);
    o.z = (short)f2bf(v.z); o.w = (short)f2bf(v.w);
    *(short4v*)(Wp + (size_t)n * 1024 + k4 * 4) = o;
  }
}

// ---- bias permute (stays f32) ----
__global__ __launch_bounds__(256) void cvt_b_kernel(const float* __restrict__ b,
                                                    float* __restrict__ bp) {
  int n = blockIdx.x * blockDim.x + threadIdx.x;
  if (n < 4096) bp[n] = b[(n & 3) * 1024 + (n >> 2)];
}

// ---- bf16 MFMA GEMM with fused x-conversion:
//   C[t][b][n] = sum_k A[n][k] * bf16(x[b][t][k]),  m = t*32+b  ----
__global__ __launch_bounds__(256) void gemm_btx(const short* __restrict__ A,
                                                const float* __restrict__ x,
                                                short* __restrict__ C) {
  const int n0 = blockIdx.x * 128;
  const int m0 = blockIdx.y * 128;
  const int tid = threadIdx.x;
  const int lane = tid & 63, wid = tid >> 6;
  const int wr = wid >> 1, wc = wid & 1;
  const int fr = lane & 15, fq = lane >> 4;

  __shared__ __align__(16) short As[128 * 32];
  __shared__ __align__(16) short Bs[128 * 32];

  f32x4 acc[4][4];
#pragma unroll
  for (int i = 0; i < 4; i++)
#pragma unroll
    for (int j = 0; j < 4; j++) acc[i][j] = (f32x4){0.f, 0.f, 0.f, 0.f};

  for (int kt = 0; kt < 1024; kt += 32) {
#pragma unroll
    for (int s = 0; s < 2; s++) {
      int c = tid + s * 256;
      int row = c >> 2;
      int off = (c & 3) * 8;
      *(u32x4*)&As[row * 32 + off] =
          *(const u32x4*)(A + (size_t)(n0 + row) * 1024 + kt + off);
      int m = m0 + row;
      int tt = m >> 5, bb = m & 31;
      const float* xp = x + ((size_t)bb * 512 + tt) * 1024 + kt + off;
      float4 va = *(const float4*)xp;
      float4 vb = *(const float4*)(xp + 4);
      short8 o;
      o[0] = (short)f2bf(va.x); o[1] = (short)f2bf(va.y);
      o[2] = (short)f2bf(va.z); o[3] = (short)f2bf(va.w);
      o[4] = (short)f2bf(vb.x); o[5] = (short)f2bf(vb.y);
      o[6] = (short)f2bf(vb.z); o[7] = (short)f2bf(vb.w);
      *(short8*)&Bs[row * 32 + off] = o;
    }
    __syncthreads();
    short8 af[4], bf[4];
#pragma unroll
    for (int i = 0; i < 4; i++)
      af[i] = *(const short8*)&As[(wr * 64 + i * 16 + fr) * 32 + fq * 8];
#pragma unroll
    for (int j = 0; j < 4; j++)
      bf[j] = *(const short8*)&Bs[(wc * 64 + j * 16 + fr) * 32 + fq * 8];
#pragma unroll
    for (int i = 0; i < 4; i++)
#pragma unroll
      for (int j = 0; j < 4; j++)
        acc[i][j] = __builtin_amdgcn_mfma_f32_16x16x32_bf16(af[i], bf[j], acc[i][j], 0, 0, 0);
    __syncthreads();
  }

#pragma unroll
  for (int i = 0; i < 4; i++) {
#pragma unroll
    for (int j = 0; j < 4; j++) {
      int nq = n0 + wr * 64 + i * 16 + fq * 4;
      int m = m0 + wc * 64 + j * 16 + fr;
      int t = m >> 5, b = m & 31;
      unsigned long long pk = 0;
#pragma unroll
      for (int r = 0; r < 4; r++)
        pk |= (unsigned long long)f2bf(acc[i][j][r]) << (16 * r);
      *(unsigned long long*)&C[(size_t)t * 131072 + (size_t)b * 4096 + nq] = pk;
    }
  }
}

// 8-chunk sentinel poll into the LDS image (uses locals soff[8], widx[8], img)
// EXACT R1 protocol.
#define POLL8(HBP)                                                            \
  do {                                                                        \
    i32x4 r0, r1, r2, r3, r4, r5, r6, r7;                                     \
    while (true) {                                                            \
      asm volatile(                                                           \
          "global_load_dwordx4 %0, %8, %16 sc0 sc1\n\t"                       \
          "global_load_dwordx4 %1, %9, %16 sc0 sc1\n\t"                       \
          "global_load_dwordx4 %2, %10, %16 sc0 sc1\n\t"                      \
          "global_load_dwordx4 %3, %11, %16 sc0 sc1\n\t"                      \
          "global_load_dwordx4 %4, %12, %16 sc0 sc1\n\t"                      \
          "global_load_dwordx4 %5, %13, %16 sc0 sc1\n\t"                      \
          "global_load_dwordx4 %6, %14, %16 sc0 sc1\n\t"                      \
          "global_load_dwordx4 %7, %15, %16 sc0 sc1\n\t"                      \
          "s_waitcnt vmcnt(0)"                                                \
          : "=&v"(r0), "=&v"(r1), "=&v"(r2), "=&v"(r3), "=&v"(r4),            \
            "=&v"(r5), "=&v"(r6), "=&v"(r7)                                   \
          : "v"(soff[0]), "v"(soff[1]), "v"(soff[2]), "v"(soff[3]),           \
            "v"(soff[4]), "v"(soff[5]), "v"(soff[6]), "v"(soff[7]),           \
            "s"(HBP)                                                          \
          : "memory");                                                        \
      u64x2 q0 = __builtin_bit_cast(u64x2, r0), q1 = __builtin_bit_cast(u64x2, r1); \
      u64x2 q2 = __builtin_bit_cast(u64x2, r2), q3 = __builtin_bit_cast(u64x2, r3); \
      u64x2 q4 = __builtin_bit_cast(u64x2, r4), q5 = __builtin_bit_cast(u64x2, r5); \
      u64x2 q6 = __builtin_bit_cast(u64x2, r6), q7 = __builtin_bit_cast(u64x2, r7); \
      unsigned long long bad =                                                \
          stale64(q0.x) | stale64(q0.y) | stale64(q1.x) | stale64(q1.y) |     \
          stale64(q2.x) | stale64(q2.y) | stale64(q3.x) | stale64(q3.y) |     \
          stale64(q4.x) | stale64(q4.y) | stale64(q5.x) | stale64(q5.y) |     \
          stale64(q6.x) | stale64(q6.y) | stale64(q7.x) | stale64(q7.y);      \
      if (!bad) break;                                                        \
    }                                                                         \
    *(i32x4*)&img[widx[0]] = r0;                                              \
    *(i32x4*)&img[widx[1]] = r1;                                              \
    *(i32x4*)&img[widx[2]] = r2;                                              \
    *(i32x4*)&img[widx[3]] = r3;                                              \
    *(i32x4*)&img[widx[4]] = r4;                                              \
    *(i32x4*)&img[widx[5]] = r5;                                              \
    *(i32x4*)&img[widx[6]] = r6;                                              \
    *(i32x4*)&img[widx[7]] = r7;                                              \
  } while (0)

// L1 MFMA block over this wave's image half (ib): 32 MFMAs, result -> S4
#define L1_MFMA(S4)                                                           \
  {                                                                           \
    f32x4 a0_ = (f32x4){0.f,0.f,0.f,0.f}, a1_ = (f32x4){0.f,0.f,0.f,0.f};     \
    f32x4 a2_ = (f32x4){0.f,0.f,0.f,0.f}, a3_ = (f32x4){0.f,0.f,0.f,0.f};     \
    _Pragma("unroll")                                                         \
    for (int m = 0; m < 8; m++) {                                             \
      const int chb = fq + m * 16;                                            \
      short8 bv0 = *(const short8*)&img[ib + fr * 1024 + (((chb + 0) ^ sw) << 3)]; \
      short8 bv1 = *(const short8*)&img[ib + fr * 1024 + (((chb + 4) ^ sw) << 3)]; \
      short8 bv2 = *(const short8*)&img[ib + fr * 1024 + (((chb + 8) ^ sw) << 3)]; \
      short8 bv3 = *(const short8*)&img[ib + fr * 1024 + (((chb + 12) ^ sw) << 3)]; \
      a0_ = __builtin_amdgcn_mfma_f32_16x16x32_bf16(wreg[4 * m + 0], bv0, a0_, 0, 0, 0); \
      a1_ = __builtin_amdgcn_mfma_f32_16x16x32_bf16(wreg[4 * m + 1], bv1, a1_, 0, 0, 0); \
      a2_ = __builtin_amdgcn_mfma_f32_16x16x32_bf16(wreg[4 * m + 2], bv2, a2_, 0, 0, 0); \
      a3_ = __builtin_amdgcn_mfma_f32_16x16x32_bf16(wreg[4 * m + 3], bv3, a3_, 0, 0, 0); \
    }                                                                         \
    S4 = (a0_ + a1_) + (a2_ + a3_);                                           \
  }

// ---- fused 2-layer pipelined LSTM ----
// grid = 192 WGs x 512 threads, all resident (1 WG/CU), no inter-group cycles.
//   WGs   0..63 : layer-0 recurrence (EXACT R8 -- proven). 2 barriers/step.
//   WGs 64..191 : layer-1, R9 delta: Wih1 path (waves 4-7) software-pipelined
//                 ONE STEP AHEAD with double-buffered red[2]: at iter t they
//                 poll h0[t+1] (L0 runs far ahead -> instant), MFMA, write
//                 red[(t+1)&1]; waves 0-3 read red[t&1] written LAST iter --
//                 no intra-step reduction wait, barrier #2 deleted (parity +
//                 end-of-step barrier give write->read ordering). 2 barriers/
//                 step (was 3). Poll/store protocol byte-identical to R8.
__global__ __launch_bounds__(512, 1) void lstm_fused(
    const short* __restrict__ gx0, const short* __restrict__ whh0,
    const float* __restrict__ b0p, const short* __restrict__ wih1,
    const short* __restrict__ whh1, const float* __restrict__ b1p,
    short* __restrict__ hs0, short* __restrict__ hs1,
    float* __restrict__ out, float* __restrict__ hn, float* __restrict__ cn) {
  const int tid = threadIdx.x;
  const int lane = tid & 63, w = tid >> 6;
  const int fr = lane & 15, fq = lane >> 4;

  __shared__ __align__(16) short img[32 * 1024];   // L0: first 16K shorts; L1: mw halves
  __shared__ __align__(16) float red[2][1024];     // L1 only: dbuf k-partial exchange

  if (blockIdx.x < 64) {
    // ================= layer 0: 128 gate-rows x 16 batches (EXACT R8) ======
    const int rg = (int)blockIdx.x >> 1, bg = (int)blockIdx.x & 1;
    const int n_base = rg * 128 + w * 16;
    const int b = bg * 16 + fr;
    const int jb = rg * 32 + w * 4;   // wave's output j-quad base
    const int j = jb + fq;
    const int sw = fr & 7;

    const short* arow = whh0 + (size_t)(n_base + fr) * 1024 + fq * 8;
    short8 wreg[32];
#pragma unroll
    for (int kk = 0; kk < 32; kk++) wreg[kk] = *(const short8*)(arow + kk * 32);

    float bia[4];
#pragma unroll
    for (int r = 0; r < 4; r++) bia[r] = b0p[n_base + fq * 4 + r];

    // stage: 2048 16B chunks of the 32KB half-image over 512 threads (4 each)
    unsigned int soff[4];
    int widx[4];
#pragma unroll
    for (int i = 0; i < 4; i++) {
      int ch = tid + i * 512;
      soff[i] = (unsigned int)ch * 16;
      int bb = ch >> 7, cc = ch & 127;
      widx[i] = bb * 1024 + ((cc ^ (bb & 7)) << 3);
    }

    float cell = 0.f;
    for (int t = 0; t < 512; ++t) {
      unsigned long long gq = *(const unsigned long long*)(
          gx0 + (size_t)t * 131072 + (size_t)b * 4096 + n_base + fq * 4);

      if (t > 0) {
        const short* hbp = hs0 + (size_t)(t - 1) * 32768 + bg * 16384;
        i32x4 r0, r1, r2, r3;
        while (true) {
          asm volatile(
              "global_load_dwordx4 %0, %4, %8 sc0 sc1\n\t"
              "global_load_dwordx4 %1, %5, %8 sc0 sc1\n\t"
              "global_load_dwordx4 %2, %6, %8 sc0 sc1\n\t"
              "global_load_dwordx4 %3, %7, %8 sc0 sc1\n\t"
              "s_waitcnt vmcnt(0)"
              : "=&v"(r0), "=&v"(r1), "=&v"(r2), "=&v"(r3)
              : "v"(soff[0]), "v"(soff[1]), "v"(soff[2]), "v"(soff[3]),
                "s"(hbp)
              : "memory");
          u64x2 q0 = __builtin_bit_cast(u64x2, r0);
          u64x2 q1 = __builtin_bit_cast(u64x2, r1);
          u64x2 q2 = __builtin_bit_cast(u64x2, r2);
          u64x2 q3 = __builtin_bit_cast(u64x2, r3);
          unsigned long long bad =
              stale64(q0.x) | stale64(q0.y) | stale64(q1.x) | stale64(q1.y) |
              stale64(q2.x) | stale64(q2.y) | stale64(q3.x) | stale64(q3.y);
          if (!bad) break;
        }
        *(i32x4*)&img[widx[0]] = r0;
        *(i32x4*)&img[widx[1]] = r1;
        *(i32x4*)&img[widx[2]] = r2;
        *(i32x4*)&img[widx[3]] = r3;
      }
      __syncthreads();  // LDS h-image ready

      f32x4 a0 = (f32x4){0.f,0.f,0.f,0.f}, a1 = (f32x4){0.f,0.f,0.f,0.f};
      f32x4 a2 = (f32x4){0.f,0.f,0.f,0.f}, a3 = (f32x4){0.f,0.f,0.f,0.f};
      if (t > 0) {
#pragma unroll
        for (int m = 0; m < 8; m++) {
          const int chb = fq + m * 16;
          short8 bv0 = *(const short8*)&img[fr * 1024 + (((chb + 0) ^ sw) << 3)];
          short8 bv1 = *(const short8*)&img[fr * 1024 + (((chb + 4) ^ sw) << 3)];
          short8 bv2 = *(const short8*)&img[fr * 1024 + (((chb + 8) ^ sw) << 3)];
          short8 bv3 = *(const short8*)&img[fr * 1024 + (((chb + 12) ^ sw) << 3)];
          a0 = __builtin_amdgcn_mfma_f32_16x16x32_bf16(wreg[4 * m + 0], bv0, a0, 0, 0, 0);
          a1 = __builtin_amdgcn_mfma_f32_16x16x32_bf16(wreg[4 * m + 1], bv1, a1, 0, 0, 0);
          a2 = __builtin_amdgcn_mfma_f32_16x16x32_bf16(wreg[4 * m + 2], bv2, a2, 0, 0, 0);
          a3 = __builtin_amdgcn_mfma_f32_16x16x32_bf16(wreg[4 * m + 3], bv3, a3, 0, 0, 0);
        }
      }

      float pre0 = (a0[0] + a1[0]) + (a2[0] + a3[0]) + bf2f((unsigned short)(gq & 0xFFFF)) + bia[0];
      float pre1 = (a0[1] + a1[1]) + (a2[1] + a3[1]) + bf2f((unsigned short)((gq >> 16) & 0xFFFF)) + bia[1];
      float pre2 = (a0[2] + a1[2]) + (a2[2] + a3[2]) + bf2f((unsigned short)((gq >> 32) & 0xFFFF)) + bia[2];
      float pre3 = (a0[3] + a1[3]) + (a2[3] + a3[3]) + bf2f((unsigned short)((gq >> 48) & 0xFFFF)) + bia[3];

      float iv = 1.f / (1.f + __expf(-pre0));
      float fv = 1.f / (1.f + __expf(-pre1));
      float gv = 2.f / (1.f + __expf(-2.f * pre2)) - 1.f;
      float ov = 1.f / (1.f + __expf(-pre3));
      cell = fv * cell + iv * gv;
      float h = ov * (2.f / (1.f + __expf(-2.f * cell)) - 1.f);

      // pack 4 gate-columns (lanes fq=0..3, same b) into one 8B coherent store
      unsigned int hu = (unsigned int)f2bf(h);
      unsigned int v1 = __shfl(hu, fr + 16);
      unsigned int v2 = __shfl(hu, fr + 32);
      unsigned int v3 = __shfl(hu, fr + 48);
      if (fq == 0) {
        unsigned long long pk = (unsigned long long)hu |
                                ((unsigned long long)v1 << 16) |
                                ((unsigned long long)v2 << 32) |
                                ((unsigned long long)v3 << 48);
        __hip_atomic_store(
            (unsigned long long*)(hs0 + (size_t)t * 32768 + (size_t)b * 1024 + jb),
            pk, __ATOMIC_RELAXED, __HIP_MEMORY_SCOPE_AGENT);
      }
      if (t == 511) {
        hn[b * 1024 + j] = h;
        cn[b * 1024 + j] = cell;
        break;
      }
      __syncthreads();  // protect LDS image until all waves' k-loop reads done
    }
  } else {
    // ===== layer 1: 64 gate-rows x 16 batches, Wih1 pipelined 1 ahead ======
    const int idx = (int)blockIdx.x - 64;
    const int rg = idx >> 1, bg = idx & 1;
    const int wn = w & 3, mw = w >> 2;        // mw=0: Whh1/h1, mw=1: Wih1/h0
    const int n_base = rg * 64 + wn * 16;
    const int b = bg * 16 + fr;
    const int jb = rg * 16 + wn * 4;
    const int j = jb + fq;
    const int sw = fr & 7;
    const int ib = mw << 14;                  // LDS image half (shorts)

    const short* wsrc = mw ? wih1 : whh1;
    const short* arow = wsrc + (size_t)(n_base + fr) * 1024 + fq * 8;
    short8 wreg[32];
#pragma unroll
    for (int kk = 0; kk < 32; kk++) wreg[kk] = *(const short8*)(arow + kk * 32);

    float bia[4];
#pragma unroll
    for (int r = 0; r < 4; r++) bia[r] = b1p[n_base + fq * 4 + r];

    // each 256-thread half stages its own 32KB image: 8 chunks/thread
    const int lt = tid & 255;
    unsigned int soff[8];
    int widx[8];
#pragma unroll
    for (int i = 0; i < 8; i++) {
      int ch = lt + i * 256;
      soff[i] = (unsigned int)ch * 16;
      int bb = ch >> 7, cc = ch & 127;
      widx[i] = ib + bb * 1024 + ((cc ^ (bb & 7)) << 3);
    }

    // ---- prologue: red[0] = Wih1 . h0[0] (computed by mw=1 waves) ----
    if (mw) {
      const short* hbp = hs0 + bg * 16384;
      POLL8(hbp);
    }
    __syncthreads();  // h0[0] image staged
    if (mw) {
      f32x4 s4;
      L1_MFMA(s4);
      *(f32x4*)&red[0][(wn * 64 + lane) * 4] = s4;
    }
    __syncthreads();  // red[0] ready; also separates prologue MFMA reads
                      // from iter-0 staging writes (cross-wave WAR)

    float cell = 0.f;
    for (int t = 0; t < 512; ++t) {
      if (mw) {
        if (t < 511) {
          const short* hbp = hs0 + (size_t)(t + 1) * 32768 + bg * 16384;
          POLL8(hbp);  // L0 runs ahead -> normally first-pull hit
        }
      } else if (t > 0) {
        const short* hbp = hs1 + (size_t)(t - 1) * 32768 + bg * 16384;
        POLL8(hbp);
      }
      __syncthreads();  // #1: images staged

      if (mw) {
        if (t < 511) {
          f32x4 s4;
          L1_MFMA(s4);
          *(f32x4*)&red[(t + 1) & 1][(wn * 64 + lane) * 4] = s4;
        }
      } else {
        f32x4 s4 = (f32x4){0.f, 0.f, 0.f, 0.f};
        if (t > 0) L1_MFMA(s4);
        const f32x4 o4 = *(const f32x4*)&red[t & 1][(wn * 64 + lane) * 4];
        float pre0 = s4[0] + o4[0] + bia[0];
        float pre1 = s4[1] + o4[1] + bia[1];
        float pre2 = s4[2] + o4[2] + bia[2];
        float pre3 = s4[3] + o4[3] + bia[3];

        float iv = 1.f / (1.f + __expf(-pre0));
        float fv = 1.f / (1.f + __expf(-pre1));
        float gv = 2.f / (1.f + __expf(-2.f * pre2)) - 1.f;
        float ov = 1.f / (1.f + __expf(-pre3));
        cell = fv * cell + iv * gv;
        float h = ov * (2.f / (1.f + __expf(-2.f * cell)) - 1.f);

        unsigned int hu = (unsigned int)f2bf(h);
        unsigned int v1 = __shfl(hu, fr + 16);
        unsigned int v2 = __shfl(hu, fr + 32);
        unsigned int v3 = __shfl(hu, fr + 48);
        if (fq == 0) {
          unsigned long long pk = (unsigned long long)hu |
                                  ((unsigned long long)v1 << 16) |
                                  ((unsigned long long)v2 << 32) |
                                  ((unsigned long long)v3 << 48);
          __hip_atomic_store(
              (unsigned long long*)(hs1 + (size_t)t * 32768 + (size_t)b * 1024 + jb),
              pk, __ATOMIC_RELAXED, __HIP_MEMORY_SCOPE_AGENT);
        }
        out[(size_t)b * 524288 + (size_t)t * 1024 + j] = h;
        if (t == 511) {
          hn[32768 + b * 1024 + j] = h;
          cn[32768 + b * 1024 + j] = cell;
        }
      }
      if (t == 511) break;
      __syncthreads();  // #2: end-of-step rendezvous; protects img + red parity
    }
  }
}

extern "C" void kernel_launch(void* const* d_in, const int* in_sizes, int n_in,
                              void* d_out, int out_size, void* d_ws, size_t ws_size,
                              hipStream_t stream) {
  const float* x    = (const float*)d_in[0];
  const float* Wih0 = (const float*)d_in[1];
  const float* b0   = (const float*)d_in[2];
  const float* Whh0 = (const float*)d_in[3];
  const float* Wih1 = (const float*)d_in[4];
  const float* b1   = (const float*)d_in[5];
  const float* Whh1 = (const float*)d_in[6];

  float* out = (float*)d_out;          // [32][512][1024]
  float* hn  = out + 16777216;         // [2][32][1024]
  float* cn  = hn + 65536;

  char* ws = (char*)d_ws;
  size_t off = 0;
  auto carve = [&](size_t bytes) {
    char* p = ws + off;
    off += (bytes + 255) & ~(size_t)255;
    return p;
  };
  short* wih0p = (short*)carve(4096ull * 1024 * 2);
  short* whh0p = (short*)carve(4096ull * 1024 * 2);
  short* wih1p = (short*)carve(4096ull * 1024 * 2);
  short* whh1p = (short*)carve(4096ull * 1024 * 2);
  float* b0p   = (float*)carve(4096 * 4);
  float* b1p   = (float*)carve(4096 * 4);
  short* gx    = (short*)carve(512ull * 4096 * 32 * 2);  // [t][b][n] layer-0 only
  short* hs0   = (short*)carve(16384ull * 1024 * 2);
  short* hs1   = (short*)carve(16384ull * 1024 * 2);

  // phase 0: weight/bias conversions + sentinel fills
  hipLaunchKernelGGL(cvt_w_kernel, dim3(1024), dim3(256), 0, stream, Wih0, wih0p);
  hipLaunchKernelGGL(cvt_w_kernel, dim3(1024), dim3(256), 0, stream, Whh0, whh0p);
  hipLaunchKernelGGL(cvt_w_kernel, dim3(1024), dim3(256), 0, stream, Wih1, wih1p);
  hipLaunchKernelGGL(cvt_w_kernel, dim3(1024), dim3(256), 0, stream, Whh1, whh1p);
  hipLaunchKernelGGL(cvt_b_kernel, dim3(16), dim3(256), 0, stream, b0, b0p);
  hipLaunchKernelGGL(cvt_b_kernel, dim3(16), dim3(256), 0, stream, b1, b1p);
  (void)hipMemsetAsync(hs0, 0x7F, 16384ull * 1024 * 2, stream);
  (void)hipMemsetAsync(hs1, 0x7F, 16384ull * 1024 * 2, stream);

  // layer-0 input GEMM with fused x->bf16 conversion (runs serially BEFORE
  // the recurrence: R6 showed concurrent bulk GEMM traffic slows the
  // latency-critical handoff chain by ~55%)
  hipLaunchKernelGGL(gemm_btx, dim3(32, 128), dim3(256), 0, stream,
                     (const short*)wih0p, x, gx);

  // fused, pipelined 2-layer recurrence: 64 layer-0 WGs + 128 layer-1 WGs
  hipLaunchKernelGGL(lstm_fused, dim3(192), dim3(512), 0, stream,
                     (const short*)gx, (const short*)whh0p, (const float*)b0p,
                     (const short*)wih1p, (const short*)whh1p, (const float*)b1p,
                     hs0, hs1, out, hn, cn);
}

// Round 10
// 2104.998 us; speedup vs baseline: 1.1244x; 1.1244x over previous
//
#include <hip/hip_runtime.h>
#include <stdint.h>

// ---- types ----
typedef __attribute__((ext_vector_type(8))) short short8;   // 8 bf16 = 4 VGPR (MFMA A/B frag)
typedef __attribute__((ext_vector_type(4))) float f32x4;    // MFMA C/D frag
typedef __attribute__((ext_vector_type(4))) unsigned int u32x4;
typedef __attribute__((ext_vector_type(4))) int i32x4;
typedef __attribute__((ext_vector_type(2))) unsigned long long u64x2;

// ---- bf16 helpers (manual RNE) ----
__device__ inline unsigned short f2bf(float f) {
  unsigned int u = __builtin_bit_cast(unsigned int, f);
  u += 0x7fffu + ((u >> 16) & 1u);
  return (unsigned short)(u >> 16);
}
__device__ inline float bf2f(unsigned short s) {
  return __builtin_bit_cast(float, (unsigned int)s << 16);
}

// convert 8 consecutive f32 at p to a short8 of bf16
__device__ inline short8 cvt8(const float* p) {
  float4 va = *(const float4*)p;
  float4 vb = *(const float4*)(p + 4);
  short8 o;
  o[0] = (short)f2bf(va.x); o[1] = (short)f2bf(va.y);
  o[2] = (short)f2bf(va.z); o[3] = (short)f2bf(va.w);
  o[4] = (short)f2bf(vb.x); o[5] = (short)f2bf(vb.y);
  o[6] = (short)f2bf(vb.z); o[7] = (short)f2bf(vb.w);
  return o;
}

// sentinel = bf16 0x7F7F (=3.39e38). |h|<1 strictly -> cannot collide with data.
// stale64(v) != 0 iff any 16-bit lane of v equals 0x7F7F.
// Protocol invariant: producers store packed 8B words; an 8B word arrives
// atomically, so "no sentinel in the pulled chunk" == chunk ready.
__device__ inline unsigned long long stale64(unsigned long long v) {
  unsigned long long x = v ^ 0x7f7f7f7f7f7f7f7full;
  return (x - 0x0001000100010001ull) & ~x & 0x8000800080008000ull;
}

// Problem constants: B=32, T=512, D=H=1024, 4H=4096, M = T*B = 16384
// gx layout: [t][b][n] bf16, n = permuted gate-row (4*j + gate)
// hs layout: [t][b][j]  bf16
// Permuted gate-row n maps to source row (n&3)*1024 + (n>>2) of the f32
// [4H][*] weight matrices (torch gate order i,f,g,o). All f32->bf16
// conversions are folded into the consumers (no cvt kernels).

// ---- bf16 MFMA GEMM, both operands converted from f32 in staging:
//   C[t][b][n] = sum_k Wih0[perm(n)][k] * bf16(x[b][t][k]),  m = t*32+b ----
__global__ __launch_bounds__(256) void gemm_btx(const float* __restrict__ W,
                                                const float* __restrict__ x,
                                                short* __restrict__ C) {
  const int n0 = blockIdx.x * 128;
  const int m0 = blockIdx.y * 128;
  const int tid = threadIdx.x;
  const int lane = tid & 63, wid = tid >> 6;
  const int wr = wid >> 1, wc = wid & 1;
  const int fr = lane & 15, fq = lane >> 4;

  __shared__ __align__(16) short As[128 * 32];
  __shared__ __align__(16) short Bs[128 * 32];

  f32x4 acc[4][4];
#pragma unroll
  for (int i = 0; i < 4; i++)
#pragma unroll
    for (int j = 0; j < 4; j++) acc[i][j] = (f32x4){0.f, 0.f, 0.f, 0.f};

  for (int kt = 0; kt < 1024; kt += 32) {
#pragma unroll
    for (int s = 0; s < 2; s++) {
      int c = tid + s * 256;
      int row = c >> 2;
      int off = (c & 3) * 8;
      int n = n0 + row;
      const float* wp =
          W + ((size_t)(n & 3) * 1024 + (n >> 2)) * 1024 + kt + off;
      *(short8*)&As[row * 32 + off] = cvt8(wp);
      int m = m0 + row;
      int tt = m >> 5, bb = m & 31;
      const float* xp = x + ((size_t)bb * 512 + tt) * 1024 + kt + off;
      *(short8*)&Bs[row * 32 + off] = cvt8(xp);
    }
    __syncthreads();
    short8 af[4], bf[4];
#pragma unroll
    for (int i = 0; i < 4; i++)
      af[i] = *(const short8*)&As[(wr * 64 + i * 16 + fr) * 32 + fq * 8];
#pragma unroll
    for (int j = 0; j < 4; j++)
      bf[j] = *(const short8*)&Bs[(wc * 64 + j * 16 + fr) * 32 + fq * 8];
#pragma unroll
    for (int i = 0; i < 4; i++)
#pragma unroll
      for (int j = 0; j < 4; j++)
        acc[i][j] = __builtin_amdgcn_mfma_f32_16x16x32_bf16(af[i], bf[j], acc[i][j], 0, 0, 0);
    __syncthreads();
  }

#pragma unroll
  for (int i = 0; i < 4; i++) {
#pragma unroll
    for (int j = 0; j < 4; j++) {
      int nq = n0 + wr * 64 + i * 16 + fq * 4;
      int m = m0 + wc * 64 + j * 16 + fr;
      int t = m >> 5, b = m & 31;
      unsigned long long pk = 0;
#pragma unroll
      for (int r = 0; r < 4; r++)
        pk |= (unsigned long long)f2bf(acc[i][j][r]) << (16 * r);
      *(unsigned long long*)&C[(size_t)t * 131072 + (size_t)b * 4096 + nq] = pk;
    }
  }
}

// 8-chunk sentinel poll into the LDS image (uses locals soff[8], widx[8], img)
// EXACT R1/R8 protocol.
#define POLL8(HBP)                                                            \
  do {                                                                        \
    i32x4 r0, r1, r2, r3, r4, r5, r6, r7;                                     \
    while (true) {                                                            \
      asm volatile(                                                           \
          "global_load_dwordx4 %0, %8, %16 sc0 sc1\n\t"                       \
          "global_load_dwordx4 %1, %9, %16 sc0 sc1\n\t"                       \
          "global_load_dwordx4 %2, %10, %16 sc0 sc1\n\t"                      \
          "global_load_dwordx4 %3, %11, %16 sc0 sc1\n\t"                      \
          "global_load_dwordx4 %4, %12, %16 sc0 sc1\n\t"                      \
          "global_load_dwordx4 %5, %13, %16 sc0 sc1\n\t"                      \
          "global_load_dwordx4 %6, %14, %16 sc0 sc1\n\t"                      \
          "global_load_dwordx4 %7, %15, %16 sc0 sc1\n\t"                      \
          "s_waitcnt vmcnt(0)"                                                \
          : "=&v"(r0), "=&v"(r1), "=&v"(r2), "=&v"(r3), "=&v"(r4),            \
            "=&v"(r5), "=&v"(r6), "=&v"(r7)                                   \
          : "v"(soff[0]), "v"(soff[1]), "v"(soff[2]), "v"(soff[3]),           \
            "v"(soff[4]), "v"(soff[5]), "v"(soff[6]), "v"(soff[7]),           \
            "s"(HBP)                                                          \
          : "memory");                                                        \
      u64x2 q0 = __builtin_bit_cast(u64x2, r0), q1 = __builtin_bit_cast(u64x2, r1); \
      u64x2 q2 = __builtin_bit_cast(u64x2, r2), q3 = __builtin_bit_cast(u64x2, r3); \
      u64x2 q4 = __builtin_bit_cast(u64x2, r4), q5 = __builtin_bit_cast(u64x2, r5); \
      u64x2 q6 = __builtin_bit_cast(u64x2, r6), q7 = __builtin_bit_cast(u64x2, r7); \
      unsigned long long bad =                                                \
          stale64(q0.x) | stale64(q0.y) | stale64(q1.x) | stale64(q1.y) |     \
          stale64(q2.x) | stale64(q2.y) | stale64(q3.x) | stale64(q3.y) |     \
          stale64(q4.x) | stale64(q4.y) | stale64(q5.x) | stale64(q5.y) |     \
          stale64(q6.x) | stale64(q6.y) | stale64(q7.x) | stale64(q7.y);      \
      if (!bad) break;                                                        \
    }                                                                         \
    *(i32x4*)&img[widx[0]] = r0;                                              \
    *(i32x4*)&img[widx[1]] = r1;                                              \
    *(i32x4*)&img[widx[2]] = r2;                                              \
    *(i32x4*)&img[widx[3]] = r3;                                              \
    *(i32x4*)&img[widx[4]] = r4;                                              \
    *(i32x4*)&img[widx[5]] = r5;                                              \
    *(i32x4*)&img[widx[6]] = r6;                                              \
    *(i32x4*)&img[widx[7]] = r7;                                              \
  } while (0)

// ---- fused 2-layer pipelined LSTM (EXACT R8 recurrence -- proven 1748us;
// only the weight/bias preload changed: reads f32 sources directly with the
// gate-permuted row index, converting in-register) ----
// grid = 192 WGs x 512 threads, all resident (1 WG/CU), no inter-group cycles.
//   WGs   0..63 : layer-0 recurrence. WG owns 128 gate-rows x 16 batches.
//   WGs 64..191 : layer-1. WG owns 64 gate-rows x 16 batches; waves 0-3 hold
//                 Whh1 (consume h1[t-1] image), waves 4-7 hold Wih1 (consume
//                 h0[t] image); partial gate sums meet in an LDS red buffer.
// hs is pre-filled with sentinel 0x7F7F; the packed 8B agent-scope h store IS
// the readiness signal. Per-step rendezvous barriers keep waves in lockstep
// (R3/R4/R9 lessons: any desynchronization multiplies poll rounds).
__global__ __launch_bounds__(512, 1) void lstm_fused(
    const short* __restrict__ gx0, const float* __restrict__ whh0f,
    const float* __restrict__ b0, const float* __restrict__ wih1f,
    const float* __restrict__ whh1f, const float* __restrict__ b1,
    short* __restrict__ hs0, short* __restrict__ hs1,
    float* __restrict__ out, float* __restrict__ hn, float* __restrict__ cn) {
  const int tid = threadIdx.x;
  const int lane = tid & 63, w = tid >> 6;
  const int fr = lane & 15, fq = lane >> 4;

  __shared__ __align__(16) short img[32 * 1024];   // L0: first 16K shorts; L1: mw halves
  __shared__ __align__(16) float red[4 * 64 * 4];  // L1 only: 4KB k-partial exchange

  if (blockIdx.x < 64) {
    // ================= layer 0: 128 gate-rows x 16 batches =================
    const int rg = (int)blockIdx.x >> 1, bg = (int)blockIdx.x & 1;
    const int n_base = rg * 128 + w * 16;
    const int b = bg * 16 + fr;
    const int jb = rg * 32 + w * 4;   // wave's output j-quad base
    const int j = jb + fq;
    const int sw = fr & 7;

    // weight preload: f32 source, permuted row, convert in-register
    const int nrow = n_base + fr;
    const float* arow =
        whh0f + ((size_t)(nrow & 3) * 1024 + (nrow >> 2)) * 1024 + fq * 8;
    short8 wreg[32];
#pragma unroll
    for (int kk = 0; kk < 32; kk++) wreg[kk] = cvt8(arow + kk * 32);

    float bia[4];
#pragma unroll
    for (int r = 0; r < 4; r++) {
      int n = n_base + fq * 4 + r;
      bia[r] = b0[(n & 3) * 1024 + (n >> 2)];
    }

    // stage: 2048 16B chunks of the 32KB half-image over 512 threads (4 each)
    unsigned int soff[4];
    int widx[4];
#pragma unroll
    for (int i = 0; i < 4; i++) {
      int ch = tid + i * 512;
      soff[i] = (unsigned int)ch * 16;
      int bb = ch >> 7, cc = ch & 127;
      widx[i] = bb * 1024 + ((cc ^ (bb & 7)) << 3);
    }

    float cell = 0.f;
    for (int t = 0; t < 512; ++t) {
      unsigned long long gq = *(const unsigned long long*)(
          gx0 + (size_t)t * 131072 + (size_t)b * 4096 + n_base + fq * 4);

      if (t > 0) {
        const short* hbp = hs0 + (size_t)(t - 1) * 32768 + bg * 16384;
        i32x4 r0, r1, r2, r3;
        while (true) {
          asm volatile(
              "global_load_dwordx4 %0, %4, %8 sc0 sc1\n\t"
              "global_load_dwordx4 %1, %5, %8 sc0 sc1\n\t"
              "global_load_dwordx4 %2, %6, %8 sc0 sc1\n\t"
              "global_load_dwordx4 %3, %7, %8 sc0 sc1\n\t"
              "s_waitcnt vmcnt(0)"
              : "=&v"(r0), "=&v"(r1), "=&v"(r2), "=&v"(r3)
              : "v"(soff[0]), "v"(soff[1]), "v"(soff[2]), "v"(soff[3]),
                "s"(hbp)
              : "memory");
          u64x2 q0 = __builtin_bit_cast(u64x2, r0);
          u64x2 q1 = __builtin_bit_cast(u64x2, r1);
          u64x2 q2 = __builtin_bit_cast(u64x2, r2);
          u64x2 q3 = __builtin_bit_cast(u64x2, r3);
          unsigned long long bad =
              stale64(q0.x) | stale64(q0.y) | stale64(q1.x) | stale64(q1.y) |
              stale64(q2.x) | stale64(q2.y) | stale64(q3.x) | stale64(q3.y);
          if (!bad) break;
        }
        *(i32x4*)&img[widx[0]] = r0;
        *(i32x4*)&img[widx[1]] = r1;
        *(i32x4*)&img[widx[2]] = r2;
        *(i32x4*)&img[widx[3]] = r3;
      }
      __syncthreads();  // LDS h-image ready

      f32x4 a0 = (f32x4){0.f,0.f,0.f,0.f}, a1 = (f32x4){0.f,0.f,0.f,0.f};
      f32x4 a2 = (f32x4){0.f,0.f,0.f,0.f}, a3 = (f32x4){0.f,0.f,0.f,0.f};
      if (t > 0) {
#pragma unroll
        for (int m = 0; m < 8; m++) {
          const int chb = fq + m * 16;
          short8 bv0 = *(const short8*)&img[fr * 1024 + (((chb + 0) ^ sw) << 3)];
          short8 bv1 = *(const short8*)&img[fr * 1024 + (((chb + 4) ^ sw) << 3)];
          short8 bv2 = *(const short8*)&img[fr * 1024 + (((chb + 8) ^ sw) << 3)];
          short8 bv3 = *(const short8*)&img[fr * 1024 + (((chb + 12) ^ sw) << 3)];
          a0 = __builtin_amdgcn_mfma_f32_16x16x32_bf16(wreg[4 * m + 0], bv0, a0, 0, 0, 0);
          a1 = __builtin_amdgcn_mfma_f32_16x16x32_bf16(wreg[4 * m + 1], bv1, a1, 0, 0, 0);
          a2 = __builtin_amdgcn_mfma_f32_16x16x32_bf16(wreg[4 * m + 2], bv2, a2, 0, 0, 0);
          a3 = __builtin_amdgcn_mfma_f32_16x16x32_bf16(wreg[4 * m + 3], bv3, a3, 0, 0, 0);
        }
      }

      float pre0 = (a0[0] + a1[0]) + (a2[0] + a3[0]) + bf2f((unsigned short)(gq & 0xFFFF)) + bia[0];
      float pre1 = (a0[1] + a1[1]) + (a2[1] + a3[1]) + bf2f((unsigned short)((gq >> 16) & 0xFFFF)) + bia[1];
      float pre2 = (a0[2] + a1[2]) + (a2[2] + a3[2]) + bf2f((unsigned short)((gq >> 32) & 0xFFFF)) + bia[2];
      float pre3 = (a0[3] + a1[3]) + (a2[3] + a3[3]) + bf2f((unsigned short)((gq >> 48) & 0xFFFF)) + bia[3];

      float iv = 1.f / (1.f + __expf(-pre0));
      float fv = 1.f / (1.f + __expf(-pre1));
      float gv = 2.f / (1.f + __expf(-2.f * pre2)) - 1.f;
      float ov = 1.f / (1.f + __expf(-pre3));
      cell = fv * cell + iv * gv;
      float h = ov * (2.f / (1.f + __expf(-2.f * cell)) - 1.f);

      // pack 4 gate-columns (lanes fq=0..3, same b) into one 8B coherent store
      unsigned int hu = (unsigned int)f2bf(h);
      unsigned int v1 = __shfl(hu, fr + 16);
      unsigned int v2 = __shfl(hu, fr + 32);
      unsigned int v3 = __shfl(hu, fr + 48);
      if (fq == 0) {
        unsigned long long pk = (unsigned long long)hu |
                                ((unsigned long long)v1 << 16) |
                                ((unsigned long long)v2 << 32) |
                                ((unsigned long long)v3 << 48);
        __hip_atomic_store(
            (unsigned long long*)(hs0 + (size_t)t * 32768 + (size_t)b * 1024 + jb),
            pk, __ATOMIC_RELAXED, __HIP_MEMORY_SCOPE_AGENT);
      }
      if (t == 511) {
        hn[b * 1024 + j] = h;
        cn[b * 1024 + j] = cell;
        break;
      }
      __syncthreads();  // protect LDS image until all waves' k-loop reads done
    }
  } else {
    // ================= layer 1: 64 gate-rows x 16 batches, dual-matrix =====
    const int idx = (int)blockIdx.x - 64;
    const int rg = idx >> 1, bg = idx & 1;
    const int wn = w & 3, mw = w >> 2;        // mw=0: Whh1/h1, mw=1: Wih1/h0
    const int n_base = rg * 64 + wn * 16;
    const int b = bg * 16 + fr;
    const int jb = rg * 16 + wn * 4;
    const int j = jb + fq;
    const int sw = fr & 7;
    const int ib = mw << 14;                  // LDS image half (shorts)

    const float* wsrc = mw ? wih1f : whh1f;
    const int nrow = n_base + fr;
    const float* arow =
        wsrc + ((size_t)(nrow & 3) * 1024 + (nrow >> 2)) * 1024 + fq * 8;
    short8 wreg[32];
#pragma unroll
    for (int kk = 0; kk < 32; kk++) wreg[kk] = cvt8(arow + kk * 32);

    float bia[4];
#pragma unroll
    for (int r = 0; r < 4; r++) {
      int n = n_base + fq * 4 + r;
      bia[r] = b1[(n & 3) * 1024 + (n >> 2)];
    }

    // each 256-thread half stages its own 32KB image: 8 chunks/thread
    const int lt = tid & 255;
    unsigned int soff[8];
    int widx[8];
#pragma unroll
    for (int i = 0; i < 8; i++) {
      int ch = lt + i * 256;
      soff[i] = (unsigned int)ch * 16;
      int bb = ch >> 7, cc = ch & 127;
      widx[i] = ib + bb * 1024 + ((cc ^ (bb & 7)) << 3);
    }

    float cell = 0.f;
    for (int t = 0; t < 512; ++t) {
      if (mw) {
        const short* hbp = hs0 + (size_t)t * 32768 + bg * 16384;
        POLL8(hbp);
      } else if (t > 0) {
        const short* hbp = hs1 + (size_t)(t - 1) * 32768 + bg * 16384;
        POLL8(hbp);
      }
      __syncthreads();  // #1: both images staged

      f32x4 a0 = (f32x4){0.f,0.f,0.f,0.f}, a1 = (f32x4){0.f,0.f,0.f,0.f};
      f32x4 a2 = (f32x4){0.f,0.f,0.f,0.f}, a3 = (f32x4){0.f,0.f,0.f,0.f};
      if (mw || t > 0) {
#pragma unroll
        for (int m = 0; m < 8; m++) {
          const int chb = fq + m * 16;
          short8 bv0 = *(const short8*)&img[ib + fr * 1024 + (((chb + 0) ^ sw) << 3)];
          short8 bv1 = *(const short8*)&img[ib + fr * 1024 + (((chb + 4) ^ sw) << 3)];
          short8 bv2 = *(const short8*)&img[ib + fr * 1024 + (((chb + 8) ^ sw) << 3)];
          short8 bv3 = *(const short8*)&img[ib + fr * 1024 + (((chb + 12) ^ sw) << 3)];
          a0 = __builtin_amdgcn_mfma_f32_16x16x32_bf16(wreg[4 * m + 0], bv0, a0, 0, 0, 0);
          a1 = __builtin_amdgcn_mfma_f32_16x16x32_bf16(wreg[4 * m + 1], bv1, a1, 0, 0, 0);
          a2 = __builtin_amdgcn_mfma_f32_16x16x32_bf16(wreg[4 * m + 2], bv2, a2, 0, 0, 0);
          a3 = __builtin_amdgcn_mfma_f32_16x16x32_bf16(wreg[4 * m + 3], bv3, a3, 0, 0, 0);
        }
      }
      f32x4 s4 = (a0 + a1) + (a2 + a3);
      if (mw) *(f32x4*)&red[(wn * 64 + lane) * 4] = s4;
      __syncthreads();  // #2: Wih1 partials visible

      if (!mw) {
        const f32x4 o4 = *(const f32x4*)&red[(wn * 64 + lane) * 4];
        float pre0 = s4[0] + o4[0] + bia[0];
        float pre1 = s4[1] + o4[1] + bia[1];
        float pre2 = s4[2] + o4[2] + bia[2];
        float pre3 = s4[3] + o4[3] + bia[3];

        float iv = 1.f / (1.f + __expf(-pre0));
        float fv = 1.f / (1.f + __expf(-pre1));
        float gv = 2.f / (1.f + __expf(-2.f * pre2)) - 1.f;
        float ov = 1.f / (1.f + __expf(-pre3));
        cell = fv * cell + iv * gv;
        float h = ov * (2.f / (1.f + __expf(-2.f * cell)) - 1.f);

        unsigned int hu = (unsigned int)f2bf(h);
        unsigned int v1 = __shfl(hu, fr + 16);
        unsigned int v2 = __shfl(hu, fr + 32);
        unsigned int v3 = __shfl(hu, fr + 48);
        if (fq == 0) {
          unsigned long long pk = (unsigned long long)hu |
                                  ((unsigned long long)v1 << 16) |
                                  ((unsigned long long)v2 << 32) |
                                  ((unsigned long long)v3 << 48);
          __hip_atomic_store(
              (unsigned long long*)(hs1 + (size_t)t * 32768 + (size_t)b * 1024 + jb),
              pk, __ATOMIC_RELAXED, __HIP_MEMORY_SCOPE_AGENT);
        }
        out[(size_t)b * 524288 + (size_t)t * 1024 + j] = h;
        if (t == 511) {
          hn[32768 + b * 1024 + j] = h;
          cn[32768 + b * 1024 + j] = cell;
        }
      }
      if (t == 511) break;
      __syncthreads();  // #3: protect LDS image/red until all reads done
    }
  }
}

extern "C" void kernel_launch(void* const* d_in, const int* in_sizes, int n_in,
                              void* d_out, int out_size, void* d_ws, size_t ws_size,
                              hipStream_t stream) {
  const float* x    = (const float*)d_in[0];
  const float* Wih0 = (const float*)d_in[1];
  const float* b0   = (const float*)d_in[2];
  const float* Whh0 = (const float*)d_in[3];
  const float* Wih1 = (const float*)d_in[4];
  const float* b1   = (const float*)d_in[5];
  const float* Whh1 = (const float*)d_in[6];

  float* out = (float*)d_out;          // [32][512][1024]
  float* hn  = out + 16777216;         // [2][32][1024]
  float* cn  = hn + 65536;

  char* ws = (char*)d_ws;
  size_t off = 0;
  auto carve = [&](size_t bytes) {
    char* p = ws + off;
    off += (bytes + 255) & ~(size_t)255;
    return p;
  };
  short* gx  = (short*)carve(512ull * 4096 * 32 * 2);  // [t][b][n] layer-0 only
  short* hs0 = (short*)carve(16384ull * 1024 * 2);
  short* hs1 = (short*)carve(16384ull * 1024 * 2);

  // sentinel fills (all weight/bias conversions are folded into consumers)
  (void)hipMemsetAsync(hs0, 0x7F, 16384ull * 1024 * 2, stream);
  (void)hipMemsetAsync(hs1, 0x7F, 16384ull * 1024 * 2, stream);

  // layer-0 input GEMM, both operands converted from f32 in staging (runs
  // serially BEFORE the recurrence: R6 showed concurrent bulk GEMM traffic
  // slows the latency-critical handoff chain by ~55%)
  hipLaunchKernelGGL(gemm_btx, dim3(32, 128), dim3(256), 0, stream,
                     Wih0, x, gx);

  // fused, pipelined 2-layer recurrence: 64 layer-0 WGs + 128 layer-1 WGs
  hipLaunchKernelGGL(lstm_fused, dim3(192), dim3(512), 0, stream,
                     (const short*)gx, Whh0, b0, Wih1, Whh1, b1,
                     hs0, hs1, out, hn, cn);
}